// Round 5
// baseline (101.795 us; speedup 1.0000x reference)
//
#include <hip/hip_runtime.h>
#include <hip/hip_cooperative_groups.h>

namespace cg = cooperative_groups;

// Problem constants (from reference)
#define T_LEN   4096
#define BKB     256            // B_ENV * K_OPT
#define OBSD    3
#define NCHUNK  256            // time chunks == grid size
#define TC      (T_LEN / NCHUNK)   // 16 steps per chunk
#define CH      (NCHUNK * BKB) // elements per summary array (65536)
#define TOT     (T_LEN * BKB)  // elements per output tensor
#define EPSF    1e-5f

// ws float layout (total 5*CH*4B = 1.31 MB):
//   [0, CH)      A   summaries, TRANSPOSED [lane][chunk]
//   [CH, 2CH)    B0  summaries, [lane][chunk]
//   [2CH, 3CH)   B1  summaries, [lane][chunk]
//   [3CH, 4CH)   s0_in incoming state, [chunk][lane]
//   [4CH, 5CH)   s1_in incoming state, [chunk][lane]

// ---- fast math helpers ----
__device__ __forceinline__ float sigmoid_f(float x) {
    return __builtin_amdgcn_rcpf(1.0f + __expf(-x));
}
__device__ __forceinline__ float silu_f(float x) { return x * sigmoid_f(x); }
__device__ __forceinline__ float softplus_f(float x) {
    return x > 15.0f ? x : __logf(1.0f + __expf(x));
}

// ---- per-thread parameter block (all uniform; compiler scalarizes) ----
struct Pars {
    float Wi[6];    // W_in (2,3) row-major
    float bi[2];
    float Wp[14];   // W_inproj (7,2) row-major
    float cw0[4], cw1[4], cb[4];   // conv_w (4,2), conv_b
    float dtb;      // dt_bias[0]
    float A;        // -exp(A_log[0])
};

__device__ __forceinline__ Pars load_pars(const float* W_in, const float* b_in,
                                          const float* W_inproj, const float* conv_w,
                                          const float* conv_b, const float* dt_bias,
                                          const float* A_log) {
    Pars p;
#pragma unroll
    for (int i = 0; i < 6; ++i) p.Wi[i] = W_in[i];
    p.bi[0] = b_in[0]; p.bi[1] = b_in[1];
#pragma unroll
    for (int i = 0; i < 14; ++i) p.Wp[i] = W_inproj[i];
#pragma unroll
    for (int k = 0; k < 4; ++k) {
        p.cw0[k] = conv_w[2 * k];
        p.cw1[k] = conv_w[2 * k + 1];
        p.cb[k]  = conv_b[k];
    }
    p.dtb = dt_bias[0];
    p.A   = -__expf(A_log[0]);
    return p;
}

struct Step {
    float a, b0, b1;     // state update s = a*s + b
    float Cv, xh0, xh1;  // C and silu'd x
    float z0, z1;        // gate pre-activations
};

__device__ __forceinline__ Step do_step(const Pars& p, float o0, float o1, float o2,
                                        float pp[4]) {
    float x0 = fmaf(p.Wi[2], o2, fmaf(p.Wi[1], o1, fmaf(p.Wi[0], o0, p.bi[0])));
    float x1 = fmaf(p.Wi[5], o2, fmaf(p.Wi[4], o1, fmaf(p.Wi[3], o0, p.bi[1])));
    float z0 = fmaf(p.Wp[1], x1, p.Wp[0] * x0);
    float z1 = fmaf(p.Wp[3], x1, p.Wp[2] * x0);
    float q0 = fmaf(p.Wp[5], x1, p.Wp[4] * x0);
    float q1 = fmaf(p.Wp[7], x1, p.Wp[6] * x0);
    float q2 = fmaf(p.Wp[9], x1, p.Wp[8] * x0);
    float q3 = fmaf(p.Wp[11], x1, p.Wp[10] * x0);
    float dtr = fmaf(p.Wp[13], x1, fmaf(p.Wp[12], x0, p.dtb));
    float dt = softplus_f(dtr);
    float c0 = fmaf(pp[0], p.cw0[0], fmaf(q0, p.cw1[0], p.cb[0]));
    float c1 = fmaf(pp[1], p.cw0[1], fmaf(q1, p.cw1[1], p.cb[1]));
    float c2 = fmaf(pp[2], p.cw0[2], fmaf(q2, p.cw1[2], p.cb[2]));
    float c3 = fmaf(pp[3], p.cw0[3], fmaf(q3, p.cw1[3], p.cb[3]));
    pp[0] = q0; pp[1] = q1; pp[2] = q2; pp[3] = q3;
    float xh0 = silu_f(c0);
    float xh1 = silu_f(c1);
    float Bv  = silu_f(c2);
    float Cv  = silu_f(c3);
    float a = __expf(p.A * dt);
    Step s;
    s.a = a;
    float xd0 = xh0 * dt, xd1 = xh1 * dt;
    s.b0 = Bv * xd0; s.b1 = Bv * xd1;
    s.Cv = Cv; s.xh0 = xh0; s.xh1 = xh1; s.z0 = z0; s.z1 = z1;
    return s;
}

// pre-conv xBC at t0-1 (zeros if t0==0, matching the reference's zero pad)
__device__ __forceinline__ void init_pp(const Pars& p, const float* __restrict__ obs,
                                        int t0, int b, float pp[4]) {
    if (t0 == 0) { pp[0] = pp[1] = pp[2] = pp[3] = 0.0f; return; }
    const float* op = obs + ((size_t)(t0 - 1) * BKB + b) * OBSD;
    float o0 = op[0], o1 = op[1], o2 = op[2];
    float x0 = fmaf(p.Wi[2], o2, fmaf(p.Wi[1], o1, fmaf(p.Wi[0], o0, p.bi[0])));
    float x1 = fmaf(p.Wi[5], o2, fmaf(p.Wi[4], o1, fmaf(p.Wi[3], o0, p.bi[1])));
    pp[0] = fmaf(p.Wp[5], x1, p.Wp[4] * x0);
    pp[1] = fmaf(p.Wp[7], x1, p.Wp[6] * x0);
    pp[2] = fmaf(p.Wp[9], x1, p.Wp[8] * x0);
    pp[3] = fmaf(p.Wp[11], x1, p.Wp[10] * x0);
}

__global__ __launch_bounds__(BKB, 1) void k_fused(
    const float* __restrict__ obs, const float* __restrict__ W_in,
    const float* __restrict__ b_in, const float* __restrict__ W_inproj,
    const float* __restrict__ conv_w, const float* __restrict__ conv_b,
    const float* __restrict__ dt_bias, const float* __restrict__ A_log,
    const float* __restrict__ Dp_, const float* __restrict__ norm_w,
    const float* __restrict__ W_out, const float* __restrict__ head,
    const float* __restrict__ log_tau, float* __restrict__ ws,
    float* __restrict__ out) {
    __shared__ float sA[NCHUNK], sB0[NCHUNK], sB1[NCHUNK];

    const int b  = threadIdx.x;   // batch lane (phases A, C)
    const int c  = blockIdx.x;    // time chunk (phases A, C)
    const int t0 = c * TC;

    Pars p = load_pars(W_in, b_in, W_inproj, conv_w, conv_b, dt_bias, A_log);
    const float Dp = Dp_[0];
    const float w0 = (W_out[0] + W_out[2]) * norm_w[0];
    const float w1 = (W_out[1] + W_out[3]) * norm_w[1];
    const float hscale = softplus_f(head[0]);
    const float itau   = __expf(-log_tau[0]);

    // ---------------- Phase A: chunk summary (steps computed, not stored) --
    {
        float pp[4];
        init_pp(p, obs, t0, b, pp);
        float Aa = 1.0f, Ba0 = 0.0f, Ba1 = 0.0f;
#pragma unroll
        for (int i = 0; i < TC; ++i) {
            const float* op = obs + ((size_t)(t0 + i) * BKB + b) * OBSD;
            Step s = do_step(p, op[0], op[1], op[2], pp);
            Aa  *= s.a;
            Ba0 = fmaf(s.a, Ba0, s.b0);
            Ba1 = fmaf(s.a, Ba1, s.b1);
        }
        // write summaries transposed [lane][chunk] (scattered 4B stores)
        ws[(size_t)b * NCHUNK + c]          = Aa;
        ws[CH + (size_t)b * NCHUNK + c]     = Ba0;
        ws[2 * CH + (size_t)b * NCHUNK + c] = Ba1;
    }

    cg::this_grid().sync();

    // ---------------- Phase B: per-lane scan; block = lane, thread = chunk --
    {
        const int lane = blockIdx.x;
        const int i    = threadIdx.x;
        const size_t base = (size_t)lane * NCHUNK + i;
        float A  = ws[base];                                 // coalesced
        float B0 = ws[CH + base];
        float B1 = ws[2 * CH + base];
        sA[i] = A; sB0[i] = B0; sB1[i] = B1;
        __syncthreads();
#pragma unroll
        for (int off = 1; off < NCHUNK; off <<= 1) {
            float pA = 1.0f, pB0 = 0.0f, pB1 = 0.0f;
            if (i >= off) { pA = sA[i - off]; pB0 = sB0[i - off]; pB1 = sB1[i - off]; }
            __syncthreads();
            B0 = fmaf(A, pB0, B0);
            B1 = fmaf(A, pB1, B1);
            A  = A * pA;
            sA[i] = A; sB0[i] = B0; sB1[i] = B1;
            __syncthreads();
        }
        // incoming state of chunk i+1 = inclusive[i] applied to s=0
        if (i < NCHUNK - 1) {
            ws[3 * CH + (size_t)(i + 1) * BKB + lane] = B0;  // [chunk][lane]
            ws[4 * CH + (size_t)(i + 1) * BKB + lane] = B1;
        }
        if (i == 0) {
            ws[3 * CH + lane] = 0.0f;
            ws[4 * CH + lane] = 0.0f;
        }
    }

    cg::this_grid().sync();

    // ---------------- Phase C: recompute steps with true state, write out --
    {
        float s0 = ws[3 * CH + (size_t)c * BKB + b];         // coalesced
        float s1 = ws[4 * CH + (size_t)c * BKB + b];
        float pp[4];
        init_pp(p, obs, t0, b, pp);
#pragma unroll
        for (int i = 0; i < TC; ++i) {
            const int t = t0 + i;
            const float* op = obs + ((size_t)t * BKB + b) * OBSD;
            Step s = do_step(p, op[0], op[1], op[2], pp);
            s0 = fmaf(s.a, s0, s.b0);
            s1 = fmaf(s.a, s1, s.b1);
            float y0 = fmaf(s.Cv, s0, s.xh0 * Dp);
            float y1 = fmaf(s.Cv, s1, s.xh1 * Dp);
            y0 *= silu_f(s.z0);
            y1 *= silu_f(s.z1);
            float r = __builtin_amdgcn_rsqf(fmaf(0.5f, y0 * y0 + y1 * y1, EPSF));
            float q = (w0 * y0 + w1 * y1) * r * hscale;
            out[(size_t)t * BKB + b]       = q;
            out[TOT + (size_t)t * BKB + b] = q * itau;
        }
    }
}

extern "C" void kernel_launch(void* const* d_in, const int* in_sizes, int n_in,
                              void* d_out, int out_size, void* d_ws, size_t ws_size,
                              hipStream_t stream) {
    const float* obs      = (const float*)d_in[0];
    const float* W_in     = (const float*)d_in[1];
    const float* b_in     = (const float*)d_in[2];
    const float* W_inproj = (const float*)d_in[3];
    const float* conv_w   = (const float*)d_in[4];
    const float* conv_b   = (const float*)d_in[5];
    const float* dt_bias  = (const float*)d_in[6];
    const float* A_log    = (const float*)d_in[7];
    const float* Dp       = (const float*)d_in[8];
    const float* norm_w   = (const float*)d_in[9];
    const float* W_out    = (const float*)d_in[10];
    const float* head     = (const float*)d_in[11];
    const float* log_tau  = (const float*)d_in[12];
    // d_in[13] = k (unused in compute)

    float* ws  = (float*)d_ws;   // needs 5*CH*4 = 1.31 MB
    float* out = (float*)d_out;

    void* args[] = {
        (void*)&obs, (void*)&W_in, (void*)&b_in, (void*)&W_inproj,
        (void*)&conv_w, (void*)&conv_b, (void*)&dt_bias, (void*)&A_log,
        (void*)&Dp, (void*)&norm_w, (void*)&W_out, (void*)&head,
        (void*)&log_tau, (void*)&ws, (void*)&out
    };
    hipLaunchCooperativeKernel((const void*)k_fused, dim3(NCHUNK), dim3(BKB),
                               args, 0, stream);
}

// Round 6
// 32.186 us; speedup vs baseline: 3.1627x; 3.1627x over previous
//
#include <hip/hip_runtime.h>

// Problem constants (from reference)
#define T_LEN   4096
#define BKB     256            // B_ENV * K_OPT
#define OBSD    3
#define NCHUNK  1024           // time chunks
#define TC      (T_LEN / NCHUNK)   // 4 steps per chunk
#define CH      (NCHUNK * BKB) // elements per summary array (262144)
#define TOT     (T_LEN * BKB)  // elements per output tensor
#define EPSF    1e-5f

// ws float layout (total 5*CH*4B = 5.24 MB):
//   [0, CH)      A_c    per-chunk decay product,   [chunk][lane]
//   [CH, 2CH)    B0_c   per-chunk affine offset 0, [chunk][lane]
//   [2CH, 3CH)   B1_c   per-chunk affine offset 1, [chunk][lane]
//   [3CH, 4CH)   s0_in  incoming state ch 0,       [chunk][lane]
//   [4CH, 5CH)   s1_in  incoming state ch 1,       [chunk][lane]

// ---- fast math helpers ----
__device__ __forceinline__ float sigmoid_f(float x) {
    return __builtin_amdgcn_rcpf(1.0f + __expf(-x));
}
__device__ __forceinline__ float silu_f(float x) { return x * sigmoid_f(x); }
__device__ __forceinline__ float softplus_f(float x) {
    return x > 15.0f ? x : __logf(1.0f + __expf(x));
}

// ---- per-thread parameter block (all uniform; compiler scalarizes) ----
struct Pars {
    float Wi[6];    // W_in (2,3) row-major
    float bi[2];
    float Wp[14];   // W_inproj (7,2) row-major
    float cw0[4], cw1[4], cb[4];   // conv_w (4,2), conv_b
    float dtb;      // dt_bias[0]
    float A;        // -exp(A_log[0])
};

__device__ __forceinline__ Pars load_pars(const float* W_in, const float* b_in,
                                          const float* W_inproj, const float* conv_w,
                                          const float* conv_b, const float* dt_bias,
                                          const float* A_log) {
    Pars p;
#pragma unroll
    for (int i = 0; i < 6; ++i) p.Wi[i] = W_in[i];
    p.bi[0] = b_in[0]; p.bi[1] = b_in[1];
#pragma unroll
    for (int i = 0; i < 14; ++i) p.Wp[i] = W_inproj[i];
#pragma unroll
    for (int k = 0; k < 4; ++k) {
        p.cw0[k] = conv_w[2 * k];
        p.cw1[k] = conv_w[2 * k + 1];
        p.cb[k]  = conv_b[k];
    }
    p.dtb = dt_bias[0];
    p.A   = -__expf(A_log[0]);
    return p;
}

struct Step {
    float a, b0, b1;     // state update s = a*s + b
    float Cv, xh0, xh1;  // C and silu'd x
    float z0, z1;        // gate pre-activations
};

__device__ __forceinline__ Step do_step(const Pars& p, float o0, float o1, float o2,
                                        float pp[4]) {
    float x0 = fmaf(p.Wi[2], o2, fmaf(p.Wi[1], o1, fmaf(p.Wi[0], o0, p.bi[0])));
    float x1 = fmaf(p.Wi[5], o2, fmaf(p.Wi[4], o1, fmaf(p.Wi[3], o0, p.bi[1])));
    float z0 = fmaf(p.Wp[1], x1, p.Wp[0] * x0);
    float z1 = fmaf(p.Wp[3], x1, p.Wp[2] * x0);
    float q0 = fmaf(p.Wp[5], x1, p.Wp[4] * x0);
    float q1 = fmaf(p.Wp[7], x1, p.Wp[6] * x0);
    float q2 = fmaf(p.Wp[9], x1, p.Wp[8] * x0);
    float q3 = fmaf(p.Wp[11], x1, p.Wp[10] * x0);
    float dtr = fmaf(p.Wp[13], x1, fmaf(p.Wp[12], x0, p.dtb));
    float dt = softplus_f(dtr);
    float c0 = fmaf(pp[0], p.cw0[0], fmaf(q0, p.cw1[0], p.cb[0]));
    float c1 = fmaf(pp[1], p.cw0[1], fmaf(q1, p.cw1[1], p.cb[1]));
    float c2 = fmaf(pp[2], p.cw0[2], fmaf(q2, p.cw1[2], p.cb[2]));
    float c3 = fmaf(pp[3], p.cw0[3], fmaf(q3, p.cw1[3], p.cb[3]));
    pp[0] = q0; pp[1] = q1; pp[2] = q2; pp[3] = q3;
    float xh0 = silu_f(c0);
    float xh1 = silu_f(c1);
    float Bv  = silu_f(c2);
    float Cv  = silu_f(c3);
    float a = __expf(p.A * dt);
    Step s;
    s.a = a;
    float xd0 = xh0 * dt, xd1 = xh1 * dt;
    s.b0 = Bv * xd0; s.b1 = Bv * xd1;
    s.Cv = Cv; s.xh0 = xh0; s.xh1 = xh1; s.z0 = z0; s.z1 = z1;
    return s;
}

// pre-conv xBC at t0-1 (zeros if t0==0, matching the reference's zero pad)
__device__ __forceinline__ void init_pp(const Pars& p, const float* __restrict__ obs,
                                        int t0, int b, float pp[4]) {
    if (t0 == 0) { pp[0] = pp[1] = pp[2] = pp[3] = 0.0f; return; }
    const float* op = obs + ((size_t)(t0 - 1) * BKB + b) * OBSD;
    float o0 = op[0], o1 = op[1], o2 = op[2];
    float x0 = fmaf(p.Wi[2], o2, fmaf(p.Wi[1], o1, fmaf(p.Wi[0], o0, p.bi[0])));
    float x1 = fmaf(p.Wi[5], o2, fmaf(p.Wi[4], o1, fmaf(p.Wi[3], o0, p.bi[1])));
    pp[0] = fmaf(p.Wp[5], x1, p.Wp[4] * x0);
    pp[1] = fmaf(p.Wp[7], x1, p.Wp[6] * x0);
    pp[2] = fmaf(p.Wp[9], x1, p.Wp[8] * x0);
    pp[3] = fmaf(p.Wp[11], x1, p.Wp[10] * x0);
}

// Kernel 1: per-(chunk, lane) affine summary of the state recurrence.
__global__ __launch_bounds__(BKB) void k_summary(
    const float* __restrict__ obs, const float* __restrict__ W_in,
    const float* __restrict__ b_in, const float* __restrict__ W_inproj,
    const float* __restrict__ conv_w, const float* __restrict__ conv_b,
    const float* __restrict__ dt_bias, const float* __restrict__ A_log,
    float* __restrict__ ws) {
    int b = threadIdx.x;
    int c = blockIdx.x;
    int t0 = c * TC;
    Pars p = load_pars(W_in, b_in, W_inproj, conv_w, conv_b, dt_bias, A_log);
    float pp[4];
    init_pp(p, obs, t0, b, pp);
    float Aa = 1.0f, Ba0 = 0.0f, Ba1 = 0.0f;
#pragma unroll
    for (int i = 0; i < TC; ++i) {
        const float* op = obs + ((size_t)(t0 + i) * BKB + b) * OBSD;
        Step s = do_step(p, op[0], op[1], op[2], pp);
        Aa  *= s.a;
        Ba0 = fmaf(s.a, Ba0, s.b0);
        Ba1 = fmaf(s.a, Ba1, s.b1);
    }
    int idx = c * BKB + b;
    ws[idx]          = Aa;       // [chunk][lane], coalesced
    ws[CH + idx]     = Ba0;
    ws[2 * CH + idx] = Ba1;
}

// Kernel 2: per-lane Hillis-Steele scan over 1024 chunks (block = lane).
// Strided reads hit L3 (ws is on-die). Writes incoming states [chunk][lane].
__global__ __launch_bounds__(NCHUNK) void k_scan(float* __restrict__ ws) {
    __shared__ float sA[NCHUNK], sB0[NCHUNK], sB1[NCHUNK];
    const int lane = blockIdx.x;
    const int i    = threadIdx.x;
    const int idx  = i * BKB + lane;
    float A  = ws[idx];
    float B0 = ws[CH + idx];
    float B1 = ws[2 * CH + idx];
    sA[i] = A; sB0[i] = B0; sB1[i] = B1;
    __syncthreads();
#pragma unroll
    for (int off = 1; off < NCHUNK; off <<= 1) {
        float pA = 1.0f, pB0 = 0.0f, pB1 = 0.0f;
        if (i >= off) { pA = sA[i - off]; pB0 = sB0[i - off]; pB1 = sB1[i - off]; }
        __syncthreads();
        B0 = fmaf(A, pB0, B0);   // compose: cur ∘ prev (prev applied first)
        B1 = fmaf(A, pB1, B1);
        A  = A * pA;
        sA[i] = A; sB0[i] = B0; sB1[i] = B1;
        __syncthreads();
    }
    // incoming state of chunk i+1 = inclusive[i] applied to s=0
    if (i < NCHUNK - 1) {
        ws[3 * CH + (size_t)(i + 1) * BKB + lane] = B0;
        ws[4 * CH + (size_t)(i + 1) * BKB + lane] = B1;
    }
    if (i == 0) {
        ws[3 * CH + lane] = 0.0f;
        ws[4 * CH + lane] = 0.0f;
    }
}

// Kernel 3: read incoming state (coalesced), recompute the chunk's 4 steps,
// write q & logits (coalesced).
__global__ __launch_bounds__(BKB) void k_apply(
    const float* __restrict__ obs, const float* __restrict__ W_in,
    const float* __restrict__ b_in, const float* __restrict__ W_inproj,
    const float* __restrict__ conv_w, const float* __restrict__ conv_b,
    const float* __restrict__ dt_bias, const float* __restrict__ A_log,
    const float* __restrict__ Dp_, const float* __restrict__ norm_w,
    const float* __restrict__ W_out, const float* __restrict__ head,
    const float* __restrict__ log_tau, const float* __restrict__ ws,
    float* __restrict__ out) {
    int b = threadIdx.x;
    int c = blockIdx.x;
    int t0 = c * TC;
    Pars p = load_pars(W_in, b_in, W_inproj, conv_w, conv_b, dt_bias, A_log);
    const float Dp = Dp_[0];
    const float w0 = (W_out[0] + W_out[2]) * norm_w[0];
    const float w1 = (W_out[1] + W_out[3]) * norm_w[1];
    const float hscale = softplus_f(head[0]);
    const float itau   = __expf(-log_tau[0]);

    float s0 = ws[3 * CH + (size_t)c * BKB + b];
    float s1 = ws[4 * CH + (size_t)c * BKB + b];

    float pp[4];
    init_pp(p, obs, t0, b, pp);
#pragma unroll
    for (int i = 0; i < TC; ++i) {
        const int t = t0 + i;
        const float* op = obs + ((size_t)t * BKB + b) * OBSD;
        Step s = do_step(p, op[0], op[1], op[2], pp);
        s0 = fmaf(s.a, s0, s.b0);
        s1 = fmaf(s.a, s1, s.b1);
        float y0 = fmaf(s.Cv, s0, s.xh0 * Dp);
        float y1 = fmaf(s.Cv, s1, s.xh1 * Dp);
        y0 *= silu_f(s.z0);
        y1 *= silu_f(s.z1);
        float r = __builtin_amdgcn_rsqf(fmaf(0.5f, y0 * y0 + y1 * y1, EPSF));
        float q = (w0 * y0 + w1 * y1) * r * hscale;
        out[(size_t)t * BKB + b]       = q;
        out[TOT + (size_t)t * BKB + b] = q * itau;
    }
}

extern "C" void kernel_launch(void* const* d_in, const int* in_sizes, int n_in,
                              void* d_out, int out_size, void* d_ws, size_t ws_size,
                              hipStream_t stream) {
    const float* obs      = (const float*)d_in[0];
    const float* W_in     = (const float*)d_in[1];
    const float* b_in     = (const float*)d_in[2];
    const float* W_inproj = (const float*)d_in[3];
    const float* conv_w   = (const float*)d_in[4];
    const float* conv_b   = (const float*)d_in[5];
    const float* dt_bias  = (const float*)d_in[6];
    const float* A_log    = (const float*)d_in[7];
    const float* Dp       = (const float*)d_in[8];
    const float* norm_w   = (const float*)d_in[9];
    const float* W_out    = (const float*)d_in[10];
    const float* head     = (const float*)d_in[11];
    const float* log_tau  = (const float*)d_in[12];
    // d_in[13] = k (unused in compute)

    float* ws  = (float*)d_ws;   // needs 5*CH*4 = 5.24 MB
    float* out = (float*)d_out;

    k_summary<<<NCHUNK, BKB, 0, stream>>>(obs, W_in, b_in, W_inproj, conv_w, conv_b,
                                          dt_bias, A_log, ws);
    k_scan<<<BKB, NCHUNK, 0, stream>>>(ws);
    k_apply<<<NCHUNK, BKB, 0, stream>>>(obs, W_in, b_in, W_inproj, conv_w, conv_b,
                                        dt_bias, A_log, Dp, norm_w, W_out, head,
                                        log_tau, ws, out);
}

// Round 7
// 24.746 us; speedup vs baseline: 4.1135x; 1.3006x over previous
//
#include <hip/hip_runtime.h>

// Problem constants (from reference)
#define T_LEN   4096
#define BKB     256            // B_ENV * K_OPT
#define OBSD    3
#define NCHUNK  512            // time chunks
#define TC      (T_LEN / NCHUNK)   // 8 steps per chunk
#define CH      (NCHUNK * BKB) // elements per summary array (131072)
#define TOT     (T_LEN * BKB)  // elements per output tensor
#define EPSF    1e-5f

// ws float layout (total 5*CH*4B = 2.62 MB):
//   [0, CH)      A_c    per-chunk decay product,   TRANSPOSED [lane][chunk]
//   [CH, 2CH)    B0_c   per-chunk affine offset 0, [lane][chunk]
//   [2CH, 3CH)   B1_c   per-chunk affine offset 1, [lane][chunk]
//   [3CH, 4CH)   s0_in  incoming state ch 0,       [chunk][lane]
//   [4CH, 5CH)   s1_in  incoming state ch 1,       [chunk][lane]

// ---- fast math helpers ----
__device__ __forceinline__ float sigmoid_f(float x) {
    return __builtin_amdgcn_rcpf(1.0f + __expf(-x));
}
__device__ __forceinline__ float silu_f(float x) { return x * sigmoid_f(x); }
__device__ __forceinline__ float softplus_f(float x) {
    return x > 15.0f ? x : __logf(1.0f + __expf(x));
}

// ---- per-thread parameter block (all uniform; compiler scalarizes) ----
struct Pars {
    float Wi[6];    // W_in (2,3) row-major
    float bi[2];
    float Wp[14];   // W_inproj (7,2) row-major
    float cw0[4], cw1[4], cb[4];   // conv_w (4,2), conv_b
    float dtb;      // dt_bias[0]
    float A;        // -exp(A_log[0])
};

__device__ __forceinline__ Pars load_pars(const float* W_in, const float* b_in,
                                          const float* W_inproj, const float* conv_w,
                                          const float* conv_b, const float* dt_bias,
                                          const float* A_log) {
    Pars p;
#pragma unroll
    for (int i = 0; i < 6; ++i) p.Wi[i] = W_in[i];
    p.bi[0] = b_in[0]; p.bi[1] = b_in[1];
#pragma unroll
    for (int i = 0; i < 14; ++i) p.Wp[i] = W_inproj[i];
#pragma unroll
    for (int k = 0; k < 4; ++k) {
        p.cw0[k] = conv_w[2 * k];
        p.cw1[k] = conv_w[2 * k + 1];
        p.cb[k]  = conv_b[k];
    }
    p.dtb = dt_bias[0];
    p.A   = -__expf(A_log[0]);
    return p;
}

struct Step {
    float a, b0, b1;     // state update s = a*s + b
    float Cv, xh0, xh1;  // C and silu'd x
    float z0, z1;        // gate pre-activations
};

__device__ __forceinline__ Step do_step(const Pars& p, float o0, float o1, float o2,
                                        float pp[4]) {
    float x0 = fmaf(p.Wi[2], o2, fmaf(p.Wi[1], o1, fmaf(p.Wi[0], o0, p.bi[0])));
    float x1 = fmaf(p.Wi[5], o2, fmaf(p.Wi[4], o1, fmaf(p.Wi[3], o0, p.bi[1])));
    float z0 = fmaf(p.Wp[1], x1, p.Wp[0] * x0);
    float z1 = fmaf(p.Wp[3], x1, p.Wp[2] * x0);
    float q0 = fmaf(p.Wp[5], x1, p.Wp[4] * x0);
    float q1 = fmaf(p.Wp[7], x1, p.Wp[6] * x0);
    float q2 = fmaf(p.Wp[9], x1, p.Wp[8] * x0);
    float q3 = fmaf(p.Wp[11], x1, p.Wp[10] * x0);
    float dtr = fmaf(p.Wp[13], x1, fmaf(p.Wp[12], x0, p.dtb));
    float dt = softplus_f(dtr);
    float c0 = fmaf(pp[0], p.cw0[0], fmaf(q0, p.cw1[0], p.cb[0]));
    float c1 = fmaf(pp[1], p.cw0[1], fmaf(q1, p.cw1[1], p.cb[1]));
    float c2 = fmaf(pp[2], p.cw0[2], fmaf(q2, p.cw1[2], p.cb[2]));
    float c3 = fmaf(pp[3], p.cw0[3], fmaf(q3, p.cw1[3], p.cb[3]));
    pp[0] = q0; pp[1] = q1; pp[2] = q2; pp[3] = q3;
    float xh0 = silu_f(c0);
    float xh1 = silu_f(c1);
    float Bv  = silu_f(c2);
    float Cv  = silu_f(c3);
    float a = __expf(p.A * dt);
    Step s;
    s.a = a;
    float xd0 = xh0 * dt, xd1 = xh1 * dt;
    s.b0 = Bv * xd0; s.b1 = Bv * xd1;
    s.Cv = Cv; s.xh0 = xh0; s.xh1 = xh1; s.z0 = z0; s.z1 = z1;
    return s;
}

// pre-conv xBC at t0-1 (zeros if t0==0, matching the reference's zero pad)
__device__ __forceinline__ void init_pp(const Pars& p, const float* __restrict__ obs,
                                        int t0, int b, float pp[4]) {
    if (t0 == 0) { pp[0] = pp[1] = pp[2] = pp[3] = 0.0f; return; }
    const float* op = obs + ((size_t)(t0 - 1) * BKB + b) * OBSD;
    float o0 = op[0], o1 = op[1], o2 = op[2];
    float x0 = fmaf(p.Wi[2], o2, fmaf(p.Wi[1], o1, fmaf(p.Wi[0], o0, p.bi[0])));
    float x1 = fmaf(p.Wi[5], o2, fmaf(p.Wi[4], o1, fmaf(p.Wi[3], o0, p.bi[1])));
    pp[0] = fmaf(p.Wp[5], x1, p.Wp[4] * x0);
    pp[1] = fmaf(p.Wp[7], x1, p.Wp[6] * x0);
    pp[2] = fmaf(p.Wp[9], x1, p.Wp[8] * x0);
    pp[3] = fmaf(p.Wp[11], x1, p.Wp[10] * x0);
}

// Kernel 1: per-(chunk, lane) affine summary, written TRANSPOSED [lane][chunk]
// (scattered stores are latency-insensitive; K2's loads become coalesced).
__global__ __launch_bounds__(BKB) void k_summary(
    const float* __restrict__ obs, const float* __restrict__ W_in,
    const float* __restrict__ b_in, const float* __restrict__ W_inproj,
    const float* __restrict__ conv_w, const float* __restrict__ conv_b,
    const float* __restrict__ dt_bias, const float* __restrict__ A_log,
    float* __restrict__ ws) {
    int b = threadIdx.x;
    int c = blockIdx.x;
    int t0 = c * TC;
    Pars p = load_pars(W_in, b_in, W_inproj, conv_w, conv_b, dt_bias, A_log);
    float pp[4];
    init_pp(p, obs, t0, b, pp);
    float Aa = 1.0f, Ba0 = 0.0f, Ba1 = 0.0f;
#pragma unroll
    for (int i = 0; i < TC; ++i) {
        const float* op = obs + ((size_t)(t0 + i) * BKB + b) * OBSD;
        Step s = do_step(p, op[0], op[1], op[2], pp);
        Aa  *= s.a;
        Ba0 = fmaf(s.a, Ba0, s.b0);
        Ba1 = fmaf(s.a, Ba1, s.b1);
    }
    size_t tbase = (size_t)b * NCHUNK + c;   // [lane][chunk]
    ws[tbase]          = Aa;
    ws[CH + tbase]     = Ba0;
    ws[2 * CH + tbase] = Ba1;
}

// Kernel 2: per-lane Hillis-Steele scan; block = lane, thread = chunk.
// Loads are COALESCED ([lane][chunk] rows); s_in written back scattered
// [chunk][lane] so K3's load is coalesced.
__global__ __launch_bounds__(NCHUNK) void k_scan(float* __restrict__ ws) {
    __shared__ float sA[NCHUNK], sB0[NCHUNK], sB1[NCHUNK];
    const int lane = blockIdx.x;
    const int i    = threadIdx.x;
    const size_t base = (size_t)lane * NCHUNK + i;
    float A  = ws[base];                     // coalesced
    float B0 = ws[CH + base];
    float B1 = ws[2 * CH + base];
    sA[i] = A; sB0[i] = B0; sB1[i] = B1;
    __syncthreads();
#pragma unroll
    for (int off = 1; off < NCHUNK; off <<= 1) {
        float pA = 1.0f, pB0 = 0.0f, pB1 = 0.0f;
        if (i >= off) { pA = sA[i - off]; pB0 = sB0[i - off]; pB1 = sB1[i - off]; }
        __syncthreads();
        B0 = fmaf(A, pB0, B0);   // compose: cur ∘ prev (prev applied first)
        B1 = fmaf(A, pB1, B1);
        A  = A * pA;
        sA[i] = A; sB0[i] = B0; sB1[i] = B1;
        __syncthreads();
    }
    // incoming state of chunk i+1 = inclusive[i] applied to s=0
    if (i < NCHUNK - 1) {
        ws[3 * CH + (size_t)(i + 1) * BKB + lane] = B0;   // scattered store
        ws[4 * CH + (size_t)(i + 1) * BKB + lane] = B1;
    }
    if (i == 0) {
        ws[3 * CH + lane] = 0.0f;
        ws[4 * CH + lane] = 0.0f;
    }
}

// Kernel 3: read incoming state (coalesced), recompute the chunk's steps,
// write q & logits (coalesced).
__global__ __launch_bounds__(BKB) void k_apply(
    const float* __restrict__ obs, const float* __restrict__ W_in,
    const float* __restrict__ b_in, const float* __restrict__ W_inproj,
    const float* __restrict__ conv_w, const float* __restrict__ conv_b,
    const float* __restrict__ dt_bias, const float* __restrict__ A_log,
    const float* __restrict__ Dp_, const float* __restrict__ norm_w,
    const float* __restrict__ W_out, const float* __restrict__ head,
    const float* __restrict__ log_tau, const float* __restrict__ ws,
    float* __restrict__ out) {
    int b = threadIdx.x;
    int c = blockIdx.x;
    int t0 = c * TC;
    Pars p = load_pars(W_in, b_in, W_inproj, conv_w, conv_b, dt_bias, A_log);
    const float Dp = Dp_[0];
    const float w0 = (W_out[0] + W_out[2]) * norm_w[0];
    const float w1 = (W_out[1] + W_out[3]) * norm_w[1];
    const float hscale = softplus_f(head[0]);
    const float itau   = __expf(-log_tau[0]);

    float s0 = ws[3 * CH + (size_t)c * BKB + b];
    float s1 = ws[4 * CH + (size_t)c * BKB + b];

    float pp[4];
    init_pp(p, obs, t0, b, pp);
#pragma unroll
    for (int i = 0; i < TC; ++i) {
        const int t = t0 + i;
        const float* op = obs + ((size_t)t * BKB + b) * OBSD;
        Step s = do_step(p, op[0], op[1], op[2], pp);
        s0 = fmaf(s.a, s0, s.b0);
        s1 = fmaf(s.a, s1, s.b1);
        float y0 = fmaf(s.Cv, s0, s.xh0 * Dp);
        float y1 = fmaf(s.Cv, s1, s.xh1 * Dp);
        y0 *= silu_f(s.z0);
        y1 *= silu_f(s.z1);
        float r = __builtin_amdgcn_rsqf(fmaf(0.5f, y0 * y0 + y1 * y1, EPSF));
        float q = (w0 * y0 + w1 * y1) * r * hscale;
        out[(size_t)t * BKB + b]       = q;
        out[TOT + (size_t)t * BKB + b] = q * itau;
    }
}

extern "C" void kernel_launch(void* const* d_in, const int* in_sizes, int n_in,
                              void* d_out, int out_size, void* d_ws, size_t ws_size,
                              hipStream_t stream) {
    const float* obs      = (const float*)d_in[0];
    const float* W_in     = (const float*)d_in[1];
    const float* b_in     = (const float*)d_in[2];
    const float* W_inproj = (const float*)d_in[3];
    const float* conv_w   = (const float*)d_in[4];
    const float* conv_b   = (const float*)d_in[5];
    const float* dt_bias  = (const float*)d_in[6];
    const float* A_log    = (const float*)d_in[7];
    const float* Dp       = (const float*)d_in[8];
    const float* norm_w   = (const float*)d_in[9];
    const float* W_out    = (const float*)d_in[10];
    const float* head     = (const float*)d_in[11];
    const float* log_tau  = (const float*)d_in[12];
    // d_in[13] = k (unused in compute)

    float* ws  = (float*)d_ws;   // needs 5*CH*4 = 2.62 MB
    float* out = (float*)d_out;

    k_summary<<<NCHUNK, BKB, 0, stream>>>(obs, W_in, b_in, W_inproj, conv_w, conv_b,
                                          dt_bias, A_log, ws);
    k_scan<<<BKB, NCHUNK, 0, stream>>>(ws);
    k_apply<<<NCHUNK, BKB, 0, stream>>>(obs, W_in, b_in, W_inproj, conv_w, conv_b,
                                        dt_bias, A_log, Dp, norm_w, W_out, head,
                                        log_tau, ws, out);
}